// Round 4
// baseline (1122.164 us; speedup 1.0000x reference)
//
#include <hip/hip_runtime.h>
#include <hip/hip_bf16.h>
#include <type_traits>

constexpr int B_ = 8, C_ = 256, P_ = 64, H_ = 64, W_ = 64, HW_ = 4096;

typedef __attribute__((ext_vector_type(8))) short short8;   // 8 bf16
typedef __attribute__((ext_vector_type(4))) short short4v;  // 4 bf16 (8 B)
typedef __attribute__((ext_vector_type(4))) float f32x4;

__device__ __forceinline__ short bfbits(float f) {
    __hip_bfloat16 h = __float2bfloat16(f);
    return *reinterpret_cast<short*>(&h);
}
__device__ __forceinline__ float bf2f(short s) {
    __hip_bfloat16 h = *reinterpret_cast<__hip_bfloat16*>(&s);
    return (float)h;
}

// ---------------------------------------------------------------------------
// K0: weight prep. w fp32 [co][ci][3][3] (OIHW) -> wb bf16 [tap][co][ci].
// ---------------------------------------------------------------------------
__global__ __launch_bounds__(256) void k_prep_w(
    const float* __restrict__ w, __hip_bfloat16* __restrict__ wb)
{
    const int i = blockIdx.x * 256 + threadIdx.x;        // over 9*256*256
    const int tap = i >> 16;
    const int co  = (i >> 8) & 255;
    const int ci  = i & 255;
    wb[i] = __float2bfloat16(w[(co * 256 + ci) * 9 + tap]);
}

// ---------------------------------------------------------------------------
// K1: 1x1 convs. GEMM [P=64, C=256] x [C, HW]. Outputs transposed bf16
// hi/lo splits [B][HW][P] — the exact operand layout k_attn's MFMA wants.
// ---------------------------------------------------------------------------
__global__ __launch_bounds__(256) void k_conv1x1(
    const float* __restrict__ x,
    const float* __restrict__ w_top, const float* __restrict__ b_top,
    const float* __restrict__ w_cen, const float* __restrict__ b_cen,
    __hip_bfloat16* __restrict__ xtTh, __hip_bfloat16* __restrict__ xtTl,
    __hip_bfloat16* __restrict__ xcTh, __hip_bfloat16* __restrict__ xcTl)
{
    const int b = blockIdx.z;
    const int n = blockIdx.x * 256 + threadIdx.x;
    const float* w    = blockIdx.y ? w_cen : w_top;
    const float* bias = blockIdx.y ? b_cen : b_top;
    __hip_bfloat16* oh = blockIdx.y ? xcTh : xtTh;
    __hip_bfloat16* ol = blockIdx.y ? xcTl : xtTl;

    const float* xp = x + (size_t)b * C_ * HW_ + n;
    float acc[P_];
#pragma unroll
    for (int p = 0; p < P_; ++p) acc[p] = 0.f;

    for (int c = 0; c < C_; c += 4) {
        const float xv0 = xp[(size_t)(c + 0) * HW_];
        const float xv1 = xp[(size_t)(c + 1) * HW_];
        const float xv2 = xp[(size_t)(c + 2) * HW_];
        const float xv3 = xp[(size_t)(c + 3) * HW_];
#pragma unroll
        for (int p = 0; p < P_; ++p) {
            const float4 wv = *reinterpret_cast<const float4*>(&w[p * C_ + c]);
            float a = acc[p];
            a = fmaf(wv.x, xv0, a);
            a = fmaf(wv.y, xv1, a);
            a = fmaf(wv.z, xv2, a);
            a = fmaf(wv.w, xv3, a);
            acc[p] = a;
        }
    }
    const size_t rbase = ((size_t)b * HW_ + n) * P_;
#pragma unroll
    for (int j = 0; j < 8; ++j) {
        short8 vh, vl;
#pragma unroll
        for (int k = 0; k < 8; ++k) {
            const float v = acc[j * 8 + k] + bias[j * 8 + k];
            const short hb = bfbits(v);
            vh[k] = hb;
            vl[k] = bfbits(v - bf2f(hb));   // residual for hi/lo split
        }
        *reinterpret_cast<short8*>(&oh[rbase + j * 8]) = vh;
        *reinterpret_cast<short8*>(&ol[rbase + j * 8]) = vl;
    }
}

// ---------------------------------------------------------------------------
// K2/K5: 3x3 conv as implicit GEMM, bf16 MFMA 16x16x32 (fp32 acc).
// Output [B][C][HW], dtype templated (bf16 for conv-bottom, fp32 for conv-out).
// ---------------------------------------------------------------------------
template <typename OT>
__global__ __launch_bounds__(256) void k_conv3x3_mfma(
    const float* __restrict__ xin, const __hip_bfloat16* __restrict__ wb,
    const float* __restrict__ bias, OT* __restrict__ out)
{
    __shared__ __align__(16) __hip_bfloat16 Xs[3][66][40];
    const int b = blockIdx.y, h = blockIdx.x;
    const int t = threadIdx.x;
    const int wave = t >> 6, lane = t & 63;
    const int lm = lane & 15, lq = lane >> 4;

    f32x4 acc[4][4];   // [n_tile][co_tile]
#pragma unroll
    for (int i = 0; i < 4; ++i)
#pragma unroll
        for (int j = 0; j < 4; ++j) acc[i][j] = f32x4{0.f, 0.f, 0.f, 0.f};

    if (t < 192) {   // zero w-halo columns once
        const int r = t >> 6, cc = t & 31, side = (t >> 5) & 1;
        Xs[r][side ? 65 : 0][cc] = __float2bfloat16(0.f);
    }

    const int ci_ld = t & 31;
    const int grp   = t >> 5;
    const float* xbase = xin + (size_t)b * C_ * HW_;

    for (int cb = 0; cb < 8; ++cb) {
        const int ci0 = cb * 32;
        __syncthreads();
#pragma unroll
        for (int it = 0; it < 6; ++it) {
            const int qr = it * 8 + grp;
            const int r = qr >> 4, wq = qr & 15;
            const int hh = h + r - 1;
            float4 v = {0.f, 0.f, 0.f, 0.f};
            if (hh >= 0 && hh < H_)
                v = *reinterpret_cast<const float4*>(
                    &xbase[(size_t)(ci0 + ci_ld) * HW_ + hh * W_ + wq * 4]);
            Xs[r][1 + wq * 4 + 0][ci_ld] = __float2bfloat16(v.x);
            Xs[r][1 + wq * 4 + 1][ci_ld] = __float2bfloat16(v.y);
            Xs[r][1 + wq * 4 + 2][ci_ld] = __float2bfloat16(v.z);
            Xs[r][1 + wq * 4 + 3][ci_ld] = __float2bfloat16(v.w);
        }
        __syncthreads();

        for (int tap = 0; tap < 9; ++tap) {
            const int dh = tap / 3;
            const int dw = tap % 3;
            short8 bf[4];
#pragma unroll
            for (int nt = 0; nt < 4; ++nt)
                bf[nt] = *reinterpret_cast<const short8*>(
                    &Xs[dh][nt * 16 + lm + dw][lq * 8]);
            short8 af[4];
            const __hip_bfloat16* wt = wb + ((size_t)tap * C_) * C_ + ci0 + lq * 8;
#pragma unroll
            for (int ct = 0; ct < 4; ++ct) {
                const int co = wave * 64 + ct * 16 + lm;
                af[ct] = *reinterpret_cast<const short8*>(&wt[(size_t)co * C_]);
            }
#pragma unroll
            for (int nt = 0; nt < 4; ++nt)
#pragma unroll
                for (int ct = 0; ct < 4; ++ct)
                    acc[nt][ct] = __builtin_amdgcn_mfma_f32_16x16x32_bf16(
                        af[ct], bf[nt], acc[nt][ct], 0, 0, 0);
        }
    }

    // Epilogue [B][C][HW]. C/D: col(n)=lane&15, row(co)=lq*4+reg.
#pragma unroll
    for (int nt = 0; nt < 4; ++nt) {
        const int pos = h * W_ + nt * 16 + lm;
#pragma unroll
        for (int ct = 0; ct < 4; ++ct) {
            const int co = wave * 64 + ct * 16 + lq * 4;
#pragma unroll
            for (int r = 0; r < 4; ++r) {
                const float v = acc[nt][ct][r] + bias[co + r];
                if constexpr (std::is_same<OT, __hip_bfloat16>::value)
                    out[((size_t)(b * C_ + co + r)) * HW_ + pos] = __float2bfloat16(v);
                else
                    out[((size_t)(b * C_ + co + r)) * HW_ + pos] = v;
            }
        }
    }
}

// ---------------------------------------------------------------------------
// K3: fused attention, all-MFMA, BARRIER-FREE main loop.
// Each wave owns a 16-row n-stripe: computes S^T (xt all-m x xc own-n) with
// hi/lo split, exps into a PRIVATE per-wave LDS region (same-wave lgkmcnt
// ordering, no __syncthreads), reads its PV A-frags back, and accumulates
// O over all 64 m-tiles. xt A-frags are wave-redundant (L1/L2-hot). The only
// barrier is the final Z block-reduction.
// ---------------------------------------------------------------------------
__global__ __launch_bounds__(256) void k_attn_mfma(
    const __hip_bfloat16* __restrict__ xtTh, const __hip_bfloat16* __restrict__ xtTl,
    const __hip_bfloat16* __restrict__ xcTh, const __hip_bfloat16* __restrict__ xcTl,
    const __hip_bfloat16* __restrict__ xb, float* __restrict__ O,
    float* __restrict__ Z)
{
    __shared__ __align__(16) short Ps[4][16][72];   // per-wave P[n16][m64], stride 72
    __shared__ float zred[4];
    const int b = blockIdx.y, n0 = blockIdx.x * 64;
    const int t = threadIdx.x, wv = t >> 6, lane = t & 63;
    const int lm = lane & 15, lq = lane >> 4;
    const int nrow = n0 + wv * 16;   // this wave's n-stripe base

    // Hoisted S^T B-frags: xc cols n (wave's own 16 rows). [kc][hi/lo]
    short8 cB[2][2];
    {
        const size_t r = ((size_t)b * HW_ + nrow + lm) * P_ + lq * 8;
#pragma unroll
        for (int kc = 0; kc < 2; ++kc) {
            cB[kc][0] = *reinterpret_cast<const short8*>(&xcTh[r + kc * 32]);
            cB[kc][1] = *reinterpret_cast<const short8*>(&xcTl[r + kc * 32]);
        }
    }

    f32x4 acc[16];   // O[own n-stripe][256 c]: 16 c-tiles
#pragma unroll
    for (int i = 0; i < 16; ++i) acc[i] = f32x4{0.f, 0.f, 0.f, 0.f};
    float zp = 0.f;

    for (int mt = 0; mt < 64; ++mt) {
        const int m0 = mt * 64;
        // S^T over 4 m-subtiles: A = xt rows m (shared across waves -> L1-hot)
#pragma unroll
        for (int ms = 0; ms < 4; ++ms) {
            const size_t ar = ((size_t)b * HW_ + m0 + ms * 16 + lm) * P_ + lq * 8;
            const short8 aH0 = *reinterpret_cast<const short8*>(&xtTh[ar]);
            const short8 aH1 = *reinterpret_cast<const short8*>(&xtTh[ar + 32]);
            const short8 aL0 = *reinterpret_cast<const short8*>(&xtTl[ar]);
            const short8 aL1 = *reinterpret_cast<const short8*>(&xtTl[ar + 32]);
            f32x4 s = {0.f, 0.f, 0.f, 0.f};
            s = __builtin_amdgcn_mfma_f32_16x16x32_bf16(aH0, cB[0][0], s, 0, 0, 0);
            s = __builtin_amdgcn_mfma_f32_16x16x32_bf16(aH1, cB[1][0], s, 0, 0, 0);
            s = __builtin_amdgcn_mfma_f32_16x16x32_bf16(aH0, cB[0][1], s, 0, 0, 0);
            s = __builtin_amdgcn_mfma_f32_16x16x32_bf16(aH1, cB[1][1], s, 0, 0, 0);
            s = __builtin_amdgcn_mfma_f32_16x16x32_bf16(aL0, cB[0][0], s, 0, 0, 0);
            s = __builtin_amdgcn_mfma_f32_16x16x32_bf16(aL1, cB[1][0], s, 0, 0, 0);
            // exp + pack into own LDS region: n = lm, m = ms*16 + lq*4 + r
            const float e0 = __expf(s[0]), e1 = __expf(s[1]);
            const float e2 = __expf(s[2]), e3 = __expf(s[3]);
            zp += (e0 + e1) + (e2 + e3);
            short4v pk = { bfbits(e0), bfbits(e1), bfbits(e2), bfbits(e3) };
            *reinterpret_cast<short4v*>(&Ps[wv][lm][ms * 16 + lq * 4]) = pk;
        }
        // PV A-frags from own region (same-wave order via lgkmcnt; no barrier)
        const short8 pa0 = *reinterpret_cast<const short8*>(&Ps[wv][lm][lq * 8]);
        const short8 pa1 = *reinterpret_cast<const short8*>(&Ps[wv][lm][32 + lq * 8]);
        // PV: B = xb[c][m] direct from global (natural conv layout, L1/L2-hot)
        const size_t xbb = ((size_t)b * C_) * HW_ + m0 + lq * 8;
#pragma unroll
        for (int ct = 0; ct < 16; ++ct) {
            const size_t cr = xbb + (size_t)(ct * 16 + lm) * HW_;
            const short8 b0 = *reinterpret_cast<const short8*>(&xb[cr]);
            const short8 b1 = *reinterpret_cast<const short8*>(&xb[cr + 32]);
            acc[ct] = __builtin_amdgcn_mfma_f32_16x16x32_bf16(pa0, b0, acc[ct], 0, 0, 0);
            acc[ct] = __builtin_amdgcn_mfma_f32_16x16x32_bf16(pa1, b1, acc[ct], 0, 0, 0);
        }
    }

    // Z: block reduction -> one atomicAdd (sole barrier in the kernel)
#pragma unroll
    for (int o = 32; o > 0; o >>= 1) zp += __shfl_down(zp, o, 64);
    if (lane == 0) zred[wv] = zp;
    __syncthreads();
    if (t == 0) atomicAdd(&Z[b], (zred[0] + zred[1]) + (zred[2] + zred[3]));

    // O[n][c] stores (coalesced along c, 64 B segments)
#pragma unroll
    for (int ct = 0; ct < 16; ++ct) {
        const int c = ct * 16 + lm;
#pragma unroll
        for (int r = 0; r < 4; ++r) {
            const int n = nrow + lq * 4 + r;
            O[((size_t)b * HW_ + n) * C_ + c] = acc[ct][r];
        }
    }
}

// ---------------------------------------------------------------------------
// K4: y = x + O*(1/Z[b]) (flat reinterpretation add; 1024 blocks per batch).
// ---------------------------------------------------------------------------
__global__ __launch_bounds__(256) void k_add(
    const float* __restrict__ x, const float* __restrict__ o,
    const float* __restrict__ Z, float* __restrict__ y)
{
    const int bidx = blockIdx.x;
    const float invZ = 1.0f / Z[bidx >> 10];
    const size_t i = ((size_t)bidx * 256 + threadIdx.x) * 4;
    const float4 a = *reinterpret_cast<const float4*>(&x[i]);
    const float4 b = *reinterpret_cast<const float4*>(&o[i]);
    float4 r{fmaf(b.x, invZ, a.x), fmaf(b.y, invZ, a.y),
             fmaf(b.z, invZ, a.z), fmaf(b.w, invZ, a.w)};
    *reinterpret_cast<float4*>(&y[i]) = r;
}

extern "C" void kernel_launch(void* const* d_in, const int* in_sizes, int n_in,
                              void* d_out, int out_size, void* d_ws, size_t ws_size,
                              hipStream_t stream)
{
    const float* x   = (const float*)d_in[0];
    const float* wt  = (const float*)d_in[1];
    const float* bt  = (const float*)d_in[2];
    const float* wc  = (const float*)d_in[3];
    const float* bc  = (const float*)d_in[4];
    const float* wbo = (const float*)d_in[5];
    const float* bbo = (const float*)d_in[6];
    const float* wo  = (const float*)d_in[7];
    const float* bo  = (const float*)d_in[8];
    float* out = (float*)d_out;

    uint8_t* w8 = (uint8_t*)d_ws;
    const size_t MB = 1u << 20;
    // Phase 1 (until k_attn done): [0,32MB) = xtT/xcT hi/lo + xb bf16
    __hip_bfloat16* xtTh = (__hip_bfloat16*)(w8);            //  4 MB
    __hip_bfloat16* xtTl = (__hip_bfloat16*)(w8 + 4 * MB);   //  4 MB
    __hip_bfloat16* xcTh = (__hip_bfloat16*)(w8 + 8 * MB);   //  4 MB
    __hip_bfloat16* xcTl = (__hip_bfloat16*)(w8 + 12 * MB);  //  4 MB
    __hip_bfloat16* xbB  = (__hip_bfloat16*)(w8 + 16 * MB);  // 16 MB
    // Phase 2: y reuses [0,32MB)
    float* y = (float*)(w8);                                 // 32 MB
    float* O = (float*)(w8 + 32 * MB);                       // 32 MB
    __hip_bfloat16* Wb1 = (__hip_bfloat16*)(w8 + 32 * MB);   // in O region (dead before attn writes O)
    __hip_bfloat16* Wb2 = (__hip_bfloat16*)(w8 + 64 * MB);   // 1.2 MB
    float* Z = (float*)(w8 + 66 * MB);

    hipMemsetAsync(Z, 0, B_ * sizeof(float), stream);
    k_prep_w<<<dim3(2304), 256, 0, stream>>>(wbo, Wb1);
    k_conv1x1<<<dim3(16, 2, 8), 256, 0, stream>>>(x, wt, bt, wc, bc,
                                                  xtTh, xtTl, xcTh, xcTl);
    k_conv3x3_mfma<__hip_bfloat16><<<dim3(64, 8), 256, 0, stream>>>(x, Wb1, bbo, xbB);
    k_attn_mfma<<<dim3(64, 8), 256, 0, stream>>>(xtTh, xtTl, xcTh, xcTl, xbB, O, Z);
    k_prep_w<<<dim3(2304), 256, 0, stream>>>(wo, Wb2);
    k_add<<<dim3(8192), 256, 0, stream>>>(x, O, Z, y);
    k_conv3x3_mfma<float><<<dim3(64, 8), 256, 0, stream>>>(y, Wb2, bo, out);
}

// Round 5
// 1033.786 us; speedup vs baseline: 1.0855x; 1.0855x over previous
//
#include <hip/hip_runtime.h>
#include <hip/hip_bf16.h>
#include <type_traits>

constexpr int B_ = 8, C_ = 256, P_ = 64, H_ = 64, W_ = 64, HW_ = 4096;

typedef __attribute__((ext_vector_type(8))) short short8;   // 8 bf16
typedef __attribute__((ext_vector_type(4))) short short4v;  // 4 bf16 (8 B)
typedef __attribute__((ext_vector_type(4))) float f32x4;

__device__ __forceinline__ short bfbits(float f) {
    __hip_bfloat16 h = __float2bfloat16(f);
    return *reinterpret_cast<short*>(&h);
}
__device__ __forceinline__ float bf2f(short s) {
    __hip_bfloat16 h = *reinterpret_cast<__hip_bfloat16*>(&s);
    return (float)h;
}

// ---------------------------------------------------------------------------
// K0: weight prep. w fp32 [co][ci][3][3] (OIHW) -> wb bf16 [tap][co][ci].
// ---------------------------------------------------------------------------
__global__ __launch_bounds__(256) void k_prep_w(
    const float* __restrict__ w, __hip_bfloat16* __restrict__ wb)
{
    const int i = blockIdx.x * 256 + threadIdx.x;        // over 9*256*256
    const int tap = i >> 16;
    const int co  = (i >> 8) & 255;
    const int ci  = i & 255;
    wb[i] = __float2bfloat16(w[(co * 256 + ci) * 9 + tap]);
}

// ---------------------------------------------------------------------------
// K1: 1x1 convs, p-quarter split for occupancy (grid 16x8x8 = 1024 blocks).
// blockIdx.y: bit2 = top/center, bits0..1 = p-quarter (16 of 64 outputs).
// ---------------------------------------------------------------------------
__global__ __launch_bounds__(256) void k_conv1x1(
    const float* __restrict__ x,
    const float* __restrict__ w_top, const float* __restrict__ b_top,
    const float* __restrict__ w_cen, const float* __restrict__ b_cen,
    __hip_bfloat16* __restrict__ xtTh, __hip_bfloat16* __restrict__ xtTl,
    __hip_bfloat16* __restrict__ xcTh, __hip_bfloat16* __restrict__ xcTl)
{
    const int b = blockIdx.z;
    const int n = blockIdx.x * 256 + threadIdx.x;
    const int conv = blockIdx.y >> 2, pq = blockIdx.y & 3;
    const int p0 = pq * 16;
    const float* w    = conv ? w_cen : w_top;
    const float* bias = conv ? b_cen : b_top;
    __hip_bfloat16* oh = conv ? xcTh : xtTh;
    __hip_bfloat16* ol = conv ? xcTl : xtTl;

    const float* xp = x + (size_t)b * C_ * HW_ + n;
    float acc[16];
#pragma unroll
    for (int p = 0; p < 16; ++p) acc[p] = 0.f;

    for (int c = 0; c < C_; c += 4) {
        const float xv0 = xp[(size_t)(c + 0) * HW_];
        const float xv1 = xp[(size_t)(c + 1) * HW_];
        const float xv2 = xp[(size_t)(c + 2) * HW_];
        const float xv3 = xp[(size_t)(c + 3) * HW_];
#pragma unroll
        for (int p = 0; p < 16; ++p) {
            const float4 wv = *reinterpret_cast<const float4*>(&w[(p0 + p) * C_ + c]);
            float a = acc[p];
            a = fmaf(wv.x, xv0, a);
            a = fmaf(wv.y, xv1, a);
            a = fmaf(wv.z, xv2, a);
            a = fmaf(wv.w, xv3, a);
            acc[p] = a;
        }
    }
    const size_t rbase = ((size_t)b * HW_ + n) * P_ + p0;
#pragma unroll
    for (int j = 0; j < 2; ++j) {
        short8 vh, vl;
#pragma unroll
        for (int k = 0; k < 8; ++k) {
            const float v = acc[j * 8 + k] + bias[p0 + j * 8 + k];
            const short hb = bfbits(v);
            vh[k] = hb;
            vl[k] = bfbits(v - bf2f(hb));   // residual for hi/lo split
        }
        *reinterpret_cast<short8*>(&oh[rbase + j * 8]) = vh;
        *reinterpret_cast<short8*>(&ol[rbase + j * 8]) = vl;
    }
}

// ---------------------------------------------------------------------------
// K2/K5: 3x3 conv as implicit GEMM, bf16 MFMA. co-half split for occupancy:
// grid (h=64, cohalf=2, b=8) = 1024 blocks; wave owns 32 co (2 co-tiles).
// ---------------------------------------------------------------------------
template <typename OT>
__global__ __launch_bounds__(256) void k_conv3x3_mfma(
    const float* __restrict__ xin, const __hip_bfloat16* __restrict__ wb,
    const float* __restrict__ bias, OT* __restrict__ out)
{
    __shared__ __align__(16) __hip_bfloat16 Xs[3][66][40];
    const int b = blockIdx.z, h = blockIdx.x, cohalf = blockIdx.y;
    const int t = threadIdx.x;
    const int wave = t >> 6, lane = t & 63;
    const int lm = lane & 15, lq = lane >> 4;
    const int cobase = cohalf * 128 + wave * 32;

    f32x4 acc[4][2];   // [n_tile][co_tile]
#pragma unroll
    for (int i = 0; i < 4; ++i)
#pragma unroll
        for (int j = 0; j < 2; ++j) acc[i][j] = f32x4{0.f, 0.f, 0.f, 0.f};

    if (t < 192) {   // zero w-halo columns once
        const int r = t >> 6, cc = t & 31, side = (t >> 5) & 1;
        Xs[r][side ? 65 : 0][cc] = __float2bfloat16(0.f);
    }

    const int ci_ld = t & 31;
    const int grp   = t >> 5;
    const float* xbase = xin + (size_t)b * C_ * HW_;

    for (int cb = 0; cb < 8; ++cb) {
        const int ci0 = cb * 32;
        __syncthreads();
#pragma unroll
        for (int it = 0; it < 6; ++it) {
            const int qr = it * 8 + grp;
            const int r = qr >> 4, wq = qr & 15;
            const int hh = h + r - 1;
            float4 v = {0.f, 0.f, 0.f, 0.f};
            if (hh >= 0 && hh < H_)
                v = *reinterpret_cast<const float4*>(
                    &xbase[(size_t)(ci0 + ci_ld) * HW_ + hh * W_ + wq * 4]);
            Xs[r][1 + wq * 4 + 0][ci_ld] = __float2bfloat16(v.x);
            Xs[r][1 + wq * 4 + 1][ci_ld] = __float2bfloat16(v.y);
            Xs[r][1 + wq * 4 + 2][ci_ld] = __float2bfloat16(v.z);
            Xs[r][1 + wq * 4 + 3][ci_ld] = __float2bfloat16(v.w);
        }
        __syncthreads();

        for (int tap = 0; tap < 9; ++tap) {
            const int dh = tap / 3;
            const int dw = tap % 3;
            short8 bf[4];
#pragma unroll
            for (int nt = 0; nt < 4; ++nt)
                bf[nt] = *reinterpret_cast<const short8*>(
                    &Xs[dh][nt * 16 + lm + dw][lq * 8]);
            short8 af[2];
            const __hip_bfloat16* wt = wb + ((size_t)tap * C_) * C_ + ci0 + lq * 8;
#pragma unroll
            for (int ct = 0; ct < 2; ++ct) {
                const int co = cobase + ct * 16 + lm;
                af[ct] = *reinterpret_cast<const short8*>(&wt[(size_t)co * C_]);
            }
#pragma unroll
            for (int nt = 0; nt < 4; ++nt)
#pragma unroll
                for (int ct = 0; ct < 2; ++ct)
                    acc[nt][ct] = __builtin_amdgcn_mfma_f32_16x16x32_bf16(
                        af[ct], bf[nt], acc[nt][ct], 0, 0, 0);
        }
    }

    // Epilogue [B][C][HW]. C/D: col(n)=lane&15, row(co)=lq*4+reg.
#pragma unroll
    for (int nt = 0; nt < 4; ++nt) {
        const int pos = h * W_ + nt * 16 + lm;
#pragma unroll
        for (int ct = 0; ct < 2; ++ct) {
            const int co = cobase + ct * 16 + lq * 4;
#pragma unroll
            for (int r = 0; r < 4; ++r) {
                const float v = acc[nt][ct][r] + bias[co + r];
                if constexpr (std::is_same<OT, __hip_bfloat16>::value)
                    out[((size_t)(b * C_ + co + r)) * HW_ + pos] = __float2bfloat16(v);
                else
                    out[((size_t)(b * C_ + co + r)) * HW_ + pos] = v;
            }
        }
    }
}

// ---------------------------------------------------------------------------
// K3: fused attention, all-MFMA, barrier-free, m-SPLIT (grid 64x2x8 = 1024
// blocks, 4/CU) + P double-buffer + S(i+1)-before-PV(i) software pipeline.
// Wave owns a 16-row n-stripe over 32 m-tiles; partial O to O0/O1 by m-half.
// ---------------------------------------------------------------------------
__global__ __launch_bounds__(256) void k_attn_mfma(
    const __hip_bfloat16* __restrict__ xtTh, const __hip_bfloat16* __restrict__ xtTl,
    const __hip_bfloat16* __restrict__ xcTh, const __hip_bfloat16* __restrict__ xcTl,
    const __hip_bfloat16* __restrict__ xb, float* __restrict__ O0,
    float* __restrict__ O1, float* __restrict__ Z)
{
    __shared__ __align__(16) short Ps[4][2][16][72];   // [wave][buf][n16][m64]
    __shared__ float zred[4];
    const int b = blockIdx.z, n0 = blockIdx.x * 64, mh = blockIdx.y;
    const int t = threadIdx.x, wv = t >> 6, lane = t & 63;
    const int lm = lane & 15, lq = lane >> 4;
    const int nrow = n0 + wv * 16;
    float* Op = mh ? O1 : O0;

    // Hoisted S^T B-frags: xc cols n (wave's own 16 rows). [kc][hi/lo]
    short8 cB[2][2];
    {
        const size_t r = ((size_t)b * HW_ + nrow + lm) * P_ + lq * 8;
#pragma unroll
        for (int kc = 0; kc < 2; ++kc) {
            cB[kc][0] = *reinterpret_cast<const short8*>(&xcTh[r + kc * 32]);
            cB[kc][1] = *reinterpret_cast<const short8*>(&xcTl[r + kc * 32]);
        }
    }

    f32x4 acc[16];   // O[own n-stripe][256 c]
#pragma unroll
    for (int i = 0; i < 16; ++i) acc[i] = f32x4{0.f, 0.f, 0.f, 0.f};
    float zp = 0.f;

    const int mt0 = mh * 32;

    auto Sphase = [&](int mt, int buf) {
        const int m0 = mt * 64;
#pragma unroll
        for (int ms = 0; ms < 4; ++ms) {
            const size_t ar = ((size_t)b * HW_ + m0 + ms * 16 + lm) * P_ + lq * 8;
            const short8 aH0 = *reinterpret_cast<const short8*>(&xtTh[ar]);
            const short8 aH1 = *reinterpret_cast<const short8*>(&xtTh[ar + 32]);
            const short8 aL0 = *reinterpret_cast<const short8*>(&xtTl[ar]);
            const short8 aL1 = *reinterpret_cast<const short8*>(&xtTl[ar + 32]);
            f32x4 s = {0.f, 0.f, 0.f, 0.f};
            s = __builtin_amdgcn_mfma_f32_16x16x32_bf16(aH0, cB[0][0], s, 0, 0, 0);
            s = __builtin_amdgcn_mfma_f32_16x16x32_bf16(aH1, cB[1][0], s, 0, 0, 0);
            s = __builtin_amdgcn_mfma_f32_16x16x32_bf16(aH0, cB[0][1], s, 0, 0, 0);
            s = __builtin_amdgcn_mfma_f32_16x16x32_bf16(aH1, cB[1][1], s, 0, 0, 0);
            s = __builtin_amdgcn_mfma_f32_16x16x32_bf16(aL0, cB[0][0], s, 0, 0, 0);
            s = __builtin_amdgcn_mfma_f32_16x16x32_bf16(aL1, cB[1][0], s, 0, 0, 0);
            const float e0 = __expf(s[0]), e1 = __expf(s[1]);
            const float e2 = __expf(s[2]), e3 = __expf(s[3]);
            zp += (e0 + e1) + (e2 + e3);
            short4v pk = { bfbits(e0), bfbits(e1), bfbits(e2), bfbits(e3) };
            *reinterpret_cast<short4v*>(&Ps[wv][buf][lm][ms * 16 + lq * 4]) = pk;
        }
    };
    auto PVphase = [&](int mt, int buf) {
        const int m0 = mt * 64;
        const short8 pa0 = *reinterpret_cast<const short8*>(&Ps[wv][buf][lm][lq * 8]);
        const short8 pa1 = *reinterpret_cast<const short8*>(&Ps[wv][buf][lm][32 + lq * 8]);
        const size_t xbb = ((size_t)b * C_) * HW_ + m0 + lq * 8;
#pragma unroll
        for (int ct = 0; ct < 16; ++ct) {
            const size_t cr = xbb + (size_t)(ct * 16 + lm) * HW_;
            const short8 b0 = *reinterpret_cast<const short8*>(&xb[cr]);
            const short8 b1 = *reinterpret_cast<const short8*>(&xb[cr + 32]);
            acc[ct] = __builtin_amdgcn_mfma_f32_16x16x32_bf16(pa0, b0, acc[ct], 0, 0, 0);
            acc[ct] = __builtin_amdgcn_mfma_f32_16x16x32_bf16(pa1, b1, acc[ct], 0, 0, 0);
        }
    };

    Sphase(mt0, 0);
    for (int i = 0; i < 31; ++i) {
        Sphase(mt0 + i + 1, (i + 1) & 1);   // next tile's loads issue early
        PVphase(mt0 + i, i & 1);            // overlaps with S of i+1
    }
    PVphase(mt0 + 31, 1);

    // Z: block reduction -> one atomicAdd (sole barrier in the kernel)
#pragma unroll
    for (int o = 32; o > 0; o >>= 1) zp += __shfl_down(zp, o, 64);
    if (lane == 0) zred[wv] = zp;
    __syncthreads();
    if (t == 0) atomicAdd(&Z[b], (zred[0] + zred[1]) + (zred[2] + zred[3]));

    // O stores (coalesced along c, 64 B segments)
#pragma unroll
    for (int ct = 0; ct < 16; ++ct) {
        const int c = ct * 16 + lm;
#pragma unroll
        for (int r = 0; r < 4; ++r) {
            const int n = nrow + lq * 4 + r;
            Op[((size_t)b * HW_ + n) * C_ + c] = acc[ct][r];
        }
    }
}

// ---------------------------------------------------------------------------
// K4: y = x + (O0+O1)*(1/Z[b]) (flat reinterpretation add).
// ---------------------------------------------------------------------------
__global__ __launch_bounds__(256) void k_add(
    const float* __restrict__ x, const float* __restrict__ o0,
    const float* __restrict__ o1, const float* __restrict__ Z,
    float* __restrict__ y)
{
    const int bidx = blockIdx.x;
    const float invZ = 1.0f / Z[bidx >> 10];
    const size_t i = ((size_t)bidx * 256 + threadIdx.x) * 4;
    const float4 a  = *reinterpret_cast<const float4*>(&x[i]);
    const float4 p0 = *reinterpret_cast<const float4*>(&o0[i]);
    const float4 p1 = *reinterpret_cast<const float4*>(&o1[i]);
    float4 r{fmaf(p0.x + p1.x, invZ, a.x), fmaf(p0.y + p1.y, invZ, a.y),
             fmaf(p0.z + p1.z, invZ, a.z), fmaf(p0.w + p1.w, invZ, a.w)};
    *reinterpret_cast<float4*>(&y[i]) = r;
}

extern "C" void kernel_launch(void* const* d_in, const int* in_sizes, int n_in,
                              void* d_out, int out_size, void* d_ws, size_t ws_size,
                              hipStream_t stream)
{
    const float* x   = (const float*)d_in[0];
    const float* wt  = (const float*)d_in[1];
    const float* bt  = (const float*)d_in[2];
    const float* wc  = (const float*)d_in[3];
    const float* bc  = (const float*)d_in[4];
    const float* wbo = (const float*)d_in[5];
    const float* bbo = (const float*)d_in[6];
    const float* wo  = (const float*)d_in[7];
    const float* bo  = (const float*)d_in[8];
    float* out = (float*)d_out;

    uint8_t* w8 = (uint8_t*)d_ws;
    const size_t MB = 1u << 20;
    // Phase 1 (until k_attn done): [0,32MB) = xtT/xcT hi/lo + xb bf16
    __hip_bfloat16* xtTh = (__hip_bfloat16*)(w8);            //  4 MB
    __hip_bfloat16* xtTl = (__hip_bfloat16*)(w8 + 4 * MB);   //  4 MB
    __hip_bfloat16* xcTh = (__hip_bfloat16*)(w8 + 8 * MB);   //  4 MB
    __hip_bfloat16* xcTl = (__hip_bfloat16*)(w8 + 12 * MB);  //  4 MB
    __hip_bfloat16* xbB  = (__hip_bfloat16*)(w8 + 16 * MB);  // 16 MB
    // Phase 2: y reuses [0,32MB)
    float* y  = (float*)(w8);                                // 32 MB
    float* O0 = (float*)(w8 + 32 * MB);                      // 32 MB
    float* O1 = out;                                         // d_out as scratch (dead until final conv)
    __hip_bfloat16* Wb1 = (__hip_bfloat16*)(w8 + 32 * MB);   // in O0 region (dead before attn writes O0)
    __hip_bfloat16* Wb2 = (__hip_bfloat16*)(w8 + 64 * MB);   // 1.2 MB
    float* Z = (float*)(w8 + 66 * MB);

    hipMemsetAsync(Z, 0, B_ * sizeof(float), stream);
    k_prep_w<<<dim3(2304), 256, 0, stream>>>(wbo, Wb1);
    k_conv1x1<<<dim3(16, 8, 8), 256, 0, stream>>>(x, wt, bt, wc, bc,
                                                  xtTh, xtTl, xcTh, xcTl);
    k_conv3x3_mfma<__hip_bfloat16><<<dim3(64, 2, 8), 256, 0, stream>>>(x, Wb1, bbo, xbB);
    k_attn_mfma<<<dim3(64, 2, 8), 256, 0, stream>>>(xtTh, xtTl, xcTh, xcTl, xbB, O0, O1, Z);
    k_prep_w<<<dim3(2304), 256, 0, stream>>>(wo, Wb2);
    k_add<<<dim3(8192), 256, 0, stream>>>(x, O0, O1, Z, y);
    k_conv3x3_mfma<float><<<dim3(64, 2, 8), 256, 0, stream>>>(y, Wb2, bo, out);
}